// Round 6
// baseline (67.913 us; speedup 1.0000x reference)
//
#include <hip/hip_runtime.h>

// KDA state update, fully vectorized 2-pass structure:
//   coef[e] = beta * (v[e] - sum_d alpha[d]*k[d]*S[d][e])
//   S_new[d][e] = alpha[d]*S[d][e] + k[d]*coef[e]
//   o[e]    = sum_d q[d] * S_new[d][e]
//
// B=64, H=32, DK=DV=128 -> 2048 heads. One WAVE (64 lanes) per head,
// 4 heads per 256-thread block. Lane owns 4 columns (float4) x 64 rows
// (half of d). The d-reduction closes with a single __shfl_xor(32) -- no
// LDS reduce, no extra barriers. Pass 2 re-reads S (L2/L3-hit; the round-5
// compiler already proved this re-read is cache-absorbed) so no 128-reg
// column residency is needed; all VMEM is 16B/lane dwordx4.
// Sout stores nontemporal: never re-read, keep L3 for S residency.

#define DK 128
#define DV 128

typedef float v4f __attribute__((ext_vector_type(4)));

__global__ __launch_bounds__(256) void kda_update_kernel(
    const float* __restrict__ S,
    const float* __restrict__ k,
    const float* __restrict__ v,
    const float* __restrict__ q,
    const float* __restrict__ alpha,
    const float* __restrict__ beta,
    float* __restrict__ Sout,
    float* __restrict__ o)
{
    const int wave  = threadIdx.x >> 6;     // 0..3 : one head per wave
    const int lane  = threadIdx.x & 63;
    const int bh    = blockIdx.x * 4 + wave;
    const int e0    = (lane & 31) * 4;      // this lane's 4 columns
    const int dbase = (lane >> 5) * 64;     // row half: 0 or 64

    __shared__ float sak[4][DK];            // alpha*k
    __shared__ float sa[4][DK];
    __shared__ float sk[4][DK];
    __shared__ float sq[4][DK];

    // Stage per-head vectors (each wave stages its own head).
    for (int i = lane; i < DK; i += 64) {
        const float kk = k[(size_t)bh * DK + i];
        const float aa = alpha[(size_t)bh * DK + i];
        sk[wave][i]  = kk;
        sa[wave][i]  = aa;
        sak[wave][i] = kk * aa;
        sq[wave][i]  = q[(size_t)bh * DK + i];
    }
    __syncthreads();

    const size_t hoff = (size_t)bh * DK * DV;
    const float* __restrict__ Sbh = S + hoff;

    // ---- Pass 1: kts[e] = sum_d alpha[d]*k[d]*S[d][e] over this half's rows.
    v4f kts = {0.f, 0.f, 0.f, 0.f};
    #pragma unroll 16
    for (int i = 0; i < 64; ++i) {
        const int d = dbase + i;
        const v4f sv = *reinterpret_cast<const v4f*>(Sbh + (size_t)d * DV + e0);
        kts += sak[wave][d] * sv;
    }
    // Close the reduction across the two row-halves (lane ^ 32).
    kts.x += __shfl_xor(kts.x, 32);
    kts.y += __shfl_xor(kts.y, 32);
    kts.z += __shfl_xor(kts.z, 32);
    kts.w += __shfl_xor(kts.w, 32);

    const float b  = beta[bh];
    const v4f  vv  = *reinterpret_cast<const v4f*>(v + (size_t)bh * DV + e0);
    const v4f  coef = b * (vv - kts);

    // ---- Pass 2: re-read S (cache-hit), compute S_new, nt-store, accumulate o.
    v4f oacc = {0.f, 0.f, 0.f, 0.f};
    float* __restrict__ Sobh = Sout + hoff;
    #pragma unroll 16
    for (int i = 0; i < 64; ++i) {
        const int d = dbase + i;
        const v4f sv = *reinterpret_cast<const v4f*>(Sbh + (size_t)d * DV + e0);
        const v4f sn = sa[wave][d] * sv + sk[wave][d] * coef;
        __builtin_nontemporal_store(sn, reinterpret_cast<v4f*>(Sobh + (size_t)d * DV + e0));
        oacc += sq[wave][d] * sn;
    }
    oacc.x += __shfl_xor(oacc.x, 32);
    oacc.y += __shfl_xor(oacc.y, 32);
    oacc.z += __shfl_xor(oacc.z, 32);
    oacc.w += __shfl_xor(oacc.w, 32);

    if (lane < 32) {
        *reinterpret_cast<v4f*>(o + (size_t)bh * DV + e0) = oacc;
    }
}

extern "C" void kernel_launch(void* const* d_in, const int* in_sizes, int n_in,
                              void* d_out, int out_size, void* d_ws, size_t ws_size,
                              hipStream_t stream) {
    const float* S     = (const float*)d_in[0];
    const float* k     = (const float*)d_in[1];
    const float* v     = (const float*)d_in[2];
    const float* q     = (const float*)d_in[3];
    const float* alpha = (const float*)d_in[4];
    const float* beta  = (const float*)d_in[5];

    const int BH = in_sizes[5];  // beta has B*H elements -> 2048 heads

    float* Sout = (float*)d_out;
    float* o    = Sout + (size_t)BH * DK * DV;

    kda_update_kernel<<<dim3(BH / 4), dim3(256), 0, stream>>>(S, k, v, q, alpha, beta, Sout, o);
}

// Round 7
// 63.434 us; speedup vs baseline: 1.0706x; 1.0706x over previous
//
#include <hip/hip_runtime.h>

// KDA state update:
//   coef[e] = beta * (v[e] - sum_d alpha[d]*k[d]*S[d][e])
//   S_new[d][e] = alpha[d]*S[d][e] + k[d]*coef[e]
//   o[e]    = sum_d q[d] * S_new[d][e]
//
// B=64, H=32, DK=DV=128 -> 2048 heads. One WAVE per head, 64 lanes x 2
// columns (float2): all reductions over d are THREAD-LOCAL (no shfl, no LDS
// reduce, single staging barrier). Explicit 2-pass read of S: pass 2 re-read
// is L2/L3-hit (round-5 empirically validated this). Each wave's per-row
// access is one contiguous 512B segment. NT stores keep Sout out of L3 so
// S stays L3-resident across graph replays.

#define DK 128
#define DV 128

typedef float v2f __attribute__((ext_vector_type(2)));

__global__ __launch_bounds__(256) void kda_update_kernel(
    const float* __restrict__ S,
    const float* __restrict__ k,
    const float* __restrict__ v,
    const float* __restrict__ q,
    const float* __restrict__ alpha,
    const float* __restrict__ beta,
    float* __restrict__ Sout,
    float* __restrict__ o)
{
    const int wave = threadIdx.x >> 6;      // 0..3 : head within block
    const int lane = threadIdx.x & 63;
    const int bh   = blockIdx.x * 4 + wave;
    const int e0   = lane * 2;              // this lane's 2 columns

    __shared__ float sak[4][DK];            // alpha*k
    __shared__ float sa[4][DK];
    __shared__ float sk[4][DK];
    __shared__ float sq[4][DK];

    // Stage per-head vectors (each wave stages its own head's vectors).
    for (int i = lane; i < DK; i += 64) {
        const float kk = k[(size_t)bh * DK + i];
        const float aa = alpha[(size_t)bh * DK + i];
        sk[wave][i]  = kk;
        sa[wave][i]  = aa;
        sak[wave][i] = kk * aa;
        sq[wave][i]  = q[(size_t)bh * DK + i];
    }
    __syncthreads();

    const size_t hoff = (size_t)bh * DK * DV;
    const float* __restrict__ Sbh = S + hoff;

    // ---- Pass 1: kts[e] = sum_d alpha[d]*k[d]*S[d][e], thread-local.
    v2f kts = {0.f, 0.f};
    #pragma unroll 32
    for (int d = 0; d < DK; ++d) {
        const v2f sv = *reinterpret_cast<const v2f*>(Sbh + (size_t)d * DV + e0);
        kts += sak[wave][d] * sv;
    }

    const v2f vv   = *reinterpret_cast<const v2f*>(v + (size_t)bh * DV + e0);
    const v2f coef = beta[bh] * (vv - kts);

    // ---- Pass 2: re-read S (cache-hit), S_new, nt-store, accumulate o.
    v2f oacc = {0.f, 0.f};
    float* __restrict__ Sobh = Sout + hoff;
    #pragma unroll 32
    for (int d = 0; d < DK; ++d) {
        const v2f sv = *reinterpret_cast<const v2f*>(Sbh + (size_t)d * DV + e0);
        const v2f sn = sa[wave][d] * sv + sk[wave][d] * coef;
        __builtin_nontemporal_store(sn, reinterpret_cast<v2f*>(Sobh + (size_t)d * DV + e0));
        oacc += sq[wave][d] * sn;
    }

    *reinterpret_cast<v2f*>(o + (size_t)bh * DV + e0) = oacc;
}

extern "C" void kernel_launch(void* const* d_in, const int* in_sizes, int n_in,
                              void* d_out, int out_size, void* d_ws, size_t ws_size,
                              hipStream_t stream) {
    const float* S     = (const float*)d_in[0];
    const float* k     = (const float*)d_in[1];
    const float* v     = (const float*)d_in[2];
    const float* q     = (const float*)d_in[3];
    const float* alpha = (const float*)d_in[4];
    const float* beta  = (const float*)d_in[5];

    const int BH = in_sizes[5];  // beta has B*H elements -> 2048 heads

    float* Sout = (float*)d_out;
    float* o    = Sout + (size_t)BH * DK * DV;

    kda_update_kernel<<<dim3(BH / 4), dim3(256), 0, stream>>>(S, k, v, q, alpha, beta, Sout, o);
}

// Round 8
// 61.970 us; speedup vs baseline: 1.0959x; 1.0236x over previous
//
#include <hip/hip_runtime.h>

// KDA state update:
//   coef[e] = beta * (v[e] - sum_d alpha[d]*k[d]*S[d][e])
//   S_new[d][e] = alpha[d]*S[d][e] + k[d]*coef[e]
//   o[e]    = sum_d q[d] * S_new[d][e]
//
// B=64, H=32, DK=DV=128 -> 2048 heads. ONE HEAD PER BLOCK (empirically
// required for S's L3 residency across graph replays: rounds 3/5 = 67.7MB
// fetch, multi-head blocks in rounds 6/7 = 133MB fetch). One wave (64 lanes)
// per block; lane owns 2 adjacent columns (float2) -> all d-reductions are
// thread-local, zero cross-lane ops, one staging barrier only. Explicit
// 2-pass read of S (pass 2 hits L2/L3 per round-5 evidence). NT stores keep
// Sout out of the caches.

#define DK 128
#define DV 128

typedef float v2f __attribute__((ext_vector_type(2)));

__global__ __launch_bounds__(64) void kda_update_kernel(
    const float* __restrict__ S,
    const float* __restrict__ k,
    const float* __restrict__ v,
    const float* __restrict__ q,
    const float* __restrict__ alpha,
    const float* __restrict__ beta,
    float* __restrict__ Sout,
    float* __restrict__ o)
{
    const int bh   = blockIdx.x;
    const int lane = threadIdx.x;       // 0..63
    const int e0   = lane * 2;          // this lane's 2 columns

    __shared__ float sak[DK];           // alpha*k
    __shared__ float sa[DK];
    __shared__ float sk[DK];
    __shared__ float sq[DK];

    // Stage per-head vectors (2 elements per lane).
    {
        const int i0 = lane * 2;
        const v2f kk = *reinterpret_cast<const v2f*>(k + (size_t)bh * DK + i0);
        const v2f aa = *reinterpret_cast<const v2f*>(alpha + (size_t)bh * DK + i0);
        const v2f qq = *reinterpret_cast<const v2f*>(q + (size_t)bh * DK + i0);
        sk[i0]  = kk.x;  sk[i0 + 1]  = kk.y;
        sa[i0]  = aa.x;  sa[i0 + 1]  = aa.y;
        sak[i0] = kk.x * aa.x;  sak[i0 + 1] = kk.y * aa.y;
        sq[i0]  = qq.x;  sq[i0 + 1]  = qq.y;
    }
    __syncthreads();

    const size_t hoff = (size_t)bh * DK * DV;
    const float* __restrict__ Sbh = S + hoff;

    // ---- Pass 1: kts[e] = sum_d alpha[d]*k[d]*S[d][e], thread-local.
    v2f kts = {0.f, 0.f};
    #pragma unroll
    for (int d = 0; d < DK; ++d) {
        const v2f sv = *reinterpret_cast<const v2f*>(Sbh + (size_t)d * DV + e0);
        kts += sak[d] * sv;
    }

    const v2f vv   = *reinterpret_cast<const v2f*>(v + (size_t)bh * DV + e0);
    const v2f coef = beta[bh] * (vv - kts);

    // ---- Pass 2: re-read S (cache-hit), S_new, nt-store, accumulate o.
    v2f oacc = {0.f, 0.f};
    float* __restrict__ Sobh = Sout + hoff;
    #pragma unroll
    for (int d = 0; d < DK; ++d) {
        const v2f sv = *reinterpret_cast<const v2f*>(Sbh + (size_t)d * DV + e0);
        const v2f sn = sa[d] * sv + sk[d] * coef;
        __builtin_nontemporal_store(sn, reinterpret_cast<v2f*>(Sobh + (size_t)d * DV + e0));
        oacc += sq[d] * sn;
    }

    *reinterpret_cast<v2f*>(o + (size_t)bh * DV + e0) = oacc;
}

extern "C" void kernel_launch(void* const* d_in, const int* in_sizes, int n_in,
                              void* d_out, int out_size, void* d_ws, size_t ws_size,
                              hipStream_t stream) {
    const float* S     = (const float*)d_in[0];
    const float* k     = (const float*)d_in[1];
    const float* v     = (const float*)d_in[2];
    const float* q     = (const float*)d_in[3];
    const float* alpha = (const float*)d_in[4];
    const float* beta  = (const float*)d_in[5];

    const int BH = in_sizes[5];  // beta has B*H elements -> 2048 heads

    float* Sout = (float*)d_out;
    float* o    = Sout + (size_t)BH * DK * DV;

    kda_update_kernel<<<dim3(BH), dim3(64), 0, stream>>>(S, k, v, q, alpha, beta, Sout, o);
}